// Round 2
// baseline (1394.739 us; speedup 1.0000x reference)
//
#include <hip/hip_runtime.h>
#include <hip/hip_bf16.h>
#include <math.h>

#define EMBED 1024
#define HEADS 16
#define HDIM 64
#define BATCH 8
#define SEQL 1024
#define MROWS (BATCH * SEQL)

// ---------------------------------------------------------------------------
// GEMM: C[M,N] = A[M,K] @ B[N,K]^T + bias[N]   (torch Linear layout)
// 128x128 tile, BK=16, 256 threads, 8x8 micro-tile per thread, fp32 VALU.
// ---------------------------------------------------------------------------
#define GT 128
#define GBK 16

__global__ __launch_bounds__(256)
void gemm_bt_bias(const float* __restrict__ A, const float* __restrict__ B,
                  const float* __restrict__ bias, float* __restrict__ C,
                  int M, int N, int K)
{
    __shared__ float As[GBK][GT + 4];   // [k][m], pad 4 -> 132 floats/row (16B-aligned rows)
    __shared__ float Bs[GBK][GT + 4];   // [k][n]
    const int bm = blockIdx.x * GT;
    const int bn = blockIdx.y * GT;
    const int tid = threadIdx.x;
    const int tm = (tid >> 4) << 3;     // 0..120
    const int tn = (tid & 15) << 3;     // 0..120

    float acc[8][8];
    #pragma unroll
    for (int i = 0; i < 8; ++i)
        #pragma unroll
        for (int j = 0; j < 8; ++j) acc[i][j] = 0.f;

    for (int k0 = 0; k0 < K; k0 += GBK) {
        #pragma unroll
        for (int i = 0; i < 2; ++i) {
            const int idx = tid + i * 256;      // 0..511 float4 units
            const int r   = idx >> 2;           // 0..127 tile row
            const int kk  = (idx & 3) << 2;     // 0,4,8,12
            const float4 a4 = *reinterpret_cast<const float4*>(
                &A[(size_t)(bm + r) * K + k0 + kk]);
            As[kk + 0][r] = a4.x; As[kk + 1][r] = a4.y;
            As[kk + 2][r] = a4.z; As[kk + 3][r] = a4.w;
            const float4 b4 = *reinterpret_cast<const float4*>(
                &B[(size_t)(bn + r) * K + k0 + kk]);
            Bs[kk + 0][r] = b4.x; Bs[kk + 1][r] = b4.y;
            Bs[kk + 2][r] = b4.z; Bs[kk + 3][r] = b4.w;
        }
        __syncthreads();
        #pragma unroll
        for (int kk = 0; kk < GBK; ++kk) {
            float a[8], b[8];
            #pragma unroll
            for (int i = 0; i < 8; ++i) a[i] = As[kk][tm + i];
            #pragma unroll
            for (int j = 0; j < 8; ++j) b[j] = Bs[kk][tn + j];
            #pragma unroll
            for (int i = 0; i < 8; ++i)
                #pragma unroll
                for (int j = 0; j < 8; ++j)
                    acc[i][j] = fmaf(a[i], b[j], acc[i][j]);
        }
        __syncthreads();
    }

    float bb[8];
    #pragma unroll
    for (int j = 0; j < 8; ++j) bb[j] = bias[bn + tn + j];
    #pragma unroll
    for (int i = 0; i < 8; ++i) {
        float4 c0, c1;
        c0.x = acc[i][0] + bb[0]; c0.y = acc[i][1] + bb[1];
        c0.z = acc[i][2] + bb[2]; c0.w = acc[i][3] + bb[3];
        c1.x = acc[i][4] + bb[4]; c1.y = acc[i][5] + bb[5];
        c1.z = acc[i][6] + bb[6]; c1.w = acc[i][7] + bb[7];
        float* cp = &C[(size_t)(bm + tm + i) * N + bn + tn];
        *reinterpret_cast<float4*>(cp)     = c0;
        *reinterpret_cast<float4*>(cp + 4) = c1;
    }
}

// ---------------------------------------------------------------------------
// Flash-style fp32 attention. One block = one (b,h) and a 64-row Q tile.
// Q/K/V live in [b, s, (h,d)] layout (row stride EMBED). KT=64 key tiles,
// online softmax. K and V share one LDS buffer: V is prefetched to regs with
// the K load and written to LDS after the score phase (K is dead by then).
// ---------------------------------------------------------------------------
#define QT 64
#define KT 64
#define KPAD 4

__global__ __launch_bounds__(256)
void attn_fwd(const float* __restrict__ Qp, const float* __restrict__ Kp,
              const float* __restrict__ Vp, float* __restrict__ Op)
{
    __shared__ float Qs[HDIM][QT + KPAD];   // [d][q], pre-scaled
    __shared__ float KVs[HDIM][KT + KPAD];  // first [d][k] (K), then [k][d] (V)
    __shared__ float Ps[QT][KT + KPAD];     // scores -> probs
    __shared__ float Mrow[QT], Lrow[QT], Arow[QT];
    __shared__ float Red1[QT][4];
    __shared__ float Red2[QT][4];

    const int tid = threadIdx.x;
    const int qt0 = blockIdx.x * QT;
    const int bh  = blockIdx.y;
    const int b   = bh >> 4;
    const int h   = bh & (HEADS - 1);
    const size_t base = (size_t)b * SEQL * EMBED + (size_t)h * HDIM;

    const float scale = 0.125f;  // 1/sqrt(64)

    // Q tile -> LDS, transposed to [d][q], scale folded in
    #pragma unroll
    for (int i = 0; i < 4; ++i) {
        const int idx = tid + i * 256;          // 0..1023
        const int qi  = idx >> 4;               // 0..63
        const int d4  = (idx & 15) << 2;        // 0..60
        const float4 q4 = *reinterpret_cast<const float4*>(
            &Qp[base + (size_t)(qt0 + qi) * EMBED + d4]);
        Qs[d4 + 0][qi] = q4.x * scale;
        Qs[d4 + 1][qi] = q4.y * scale;
        Qs[d4 + 2][qi] = q4.z * scale;
        Qs[d4 + 3][qi] = q4.w * scale;
    }
    if (tid < QT) { Mrow[tid] = -INFINITY; Lrow[tid] = 0.f; }

    const int tq  = (tid >> 4) << 2;   // score/output row group
    const int tk  = (tid & 15) << 2;   // score col group / output d group
    const int row = tid >> 2;          // softmax row
    const int sg4 = tid & 3;           // softmax segment id
    const int seg = sg4 << 4;          // segment start col

    float oacc[4][4];
    #pragma unroll
    for (int i = 0; i < 4; ++i)
        #pragma unroll
        for (int j = 0; j < 4; ++j) oacc[i][j] = 0.f;

    float (*Vs)[KT + KPAD] = KVs;      // [k][d] view of the shared buffer

    for (int kt = 0; kt < SEQL / KT; ++kt) {
        __syncthreads();   // prev iteration's Ps/Vs reads complete

        // K tile -> LDS transposed [d][k]; V tile -> registers (hide latency)
        float4 vreg[4];
        #pragma unroll
        for (int i = 0; i < 4; ++i) {
            const int idx = tid + i * 256;
            const int kj  = idx >> 4;
            const int d4  = (idx & 15) << 2;
            const size_t roff = base + (size_t)(kt * KT + kj) * EMBED + d4;
            const float4 k4 = *reinterpret_cast<const float4*>(&Kp[roff]);
            KVs[d4 + 0][kj] = k4.x;
            KVs[d4 + 1][kj] = k4.y;
            KVs[d4 + 2][kj] = k4.z;
            KVs[d4 + 3][kj] = k4.w;
            vreg[i] = *reinterpret_cast<const float4*>(&Vp[roff]);
        }
        __syncthreads();

        // scores: s[i][j] = sum_d Qs[d][tq+i] * K[d][tk+j]
        float s[4][4];
        #pragma unroll
        for (int i = 0; i < 4; ++i)
            #pragma unroll
            for (int j = 0; j < 4; ++j) s[i][j] = 0.f;
        #pragma unroll 8
        for (int d = 0; d < HDIM; ++d) {
            float qa[4], kb[4];
            #pragma unroll
            for (int i = 0; i < 4; ++i) qa[i] = Qs[d][tq + i];
            #pragma unroll
            for (int j = 0; j < 4; ++j) kb[j] = KVs[d][tk + j];
            #pragma unroll
            for (int i = 0; i < 4; ++i)
                #pragma unroll
                for (int j = 0; j < 4; ++j)
                    s[i][j] = fmaf(qa[i], kb[j], s[i][j]);
        }
        #pragma unroll
        for (int i = 0; i < 4; ++i) {
            const float4 sv = make_float4(s[i][0], s[i][1], s[i][2], s[i][3]);
            *reinterpret_cast<float4*>(&Ps[tq + i][tk]) = sv;
        }
        __syncthreads();

        // V regs -> LDS as [k][d] (K data dead now)
        #pragma unroll
        for (int i = 0; i < 4; ++i) {
            const int idx = tid + i * 256;
            const int kj  = idx >> 4;
            const int d4  = (idx & 15) << 2;
            *reinterpret_cast<float4*>(&Vs[kj][d4]) = vreg[i];
        }

        // softmax phase A: per-segment max
        const float Mold = Mrow[row];
        float pm = -INFINITY;
        #pragma unroll
        for (int c = 0; c < 16; ++c) pm = fmaxf(pm, Ps[row][seg + c]);
        Red1[row][sg4] = pm;
        __syncthreads();

        // phase B: new running max, exp, partial sums
        const float mt = fmaxf(fmaxf(Red1[row][0], Red1[row][1]),
                               fmaxf(Red1[row][2], Red1[row][3]));
        const float Mnew  = fmaxf(Mold, mt);
        const float alpha = __expf(Mold - Mnew);
        float ps = 0.f;
        #pragma unroll
        for (int c = 0; c < 16; ++c) {
            const float p = __expf(Ps[row][seg + c] - Mnew);
            Ps[row][seg + c] = p;
            ps += p;
        }
        Red2[row][sg4] = ps;
        if (sg4 == 0) { Arow[row] = alpha; Mrow[row] = Mnew; }
        __syncthreads();

        // phase C: L update, rescale accumulators, PV
        if (sg4 == 0) {
            Lrow[row] = Lrow[row] * alpha +
                        Red2[row][0] + Red2[row][1] + Red2[row][2] + Red2[row][3];
        }
        float ar[4];
        #pragma unroll
        for (int i = 0; i < 4; ++i) ar[i] = Arow[tq + i];
        #pragma unroll
        for (int i = 0; i < 4; ++i)
            #pragma unroll
            for (int j = 0; j < 4; ++j) oacc[i][j] *= ar[i];

        #pragma unroll 4
        for (int kj = 0; kj < KT; kj += 4) {
            float pmat[4][4];
            #pragma unroll
            for (int i = 0; i < 4; ++i) {
                const float4 p4 = *reinterpret_cast<const float4*>(&Ps[tq + i][kj]);
                pmat[i][0] = p4.x; pmat[i][1] = p4.y;
                pmat[i][2] = p4.z; pmat[i][3] = p4.w;
            }
            #pragma unroll
            for (int r = 0; r < 4; ++r) {
                const float4 vv = *reinterpret_cast<const float4*>(&Vs[kj + r][tk]);
                #pragma unroll
                for (int i = 0; i < 4; ++i) {
                    oacc[i][0] = fmaf(pmat[i][r], vv.x, oacc[i][0]);
                    oacc[i][1] = fmaf(pmat[i][r], vv.y, oacc[i][1]);
                    oacc[i][2] = fmaf(pmat[i][r], vv.z, oacc[i][2]);
                    oacc[i][3] = fmaf(pmat[i][r], vv.w, oacc[i][3]);
                }
            }
        }
    }
    __syncthreads();

    #pragma unroll
    for (int i = 0; i < 4; ++i) {
        const float rl = 1.f / Lrow[tq + i];
        float4 o;
        o.x = oacc[i][0] * rl; o.y = oacc[i][1] * rl;
        o.z = oacc[i][2] * rl; o.w = oacc[i][3] * rl;
        *reinterpret_cast<float4*>(
            &Op[base + (size_t)(qt0 + tq + i) * EMBED + tk]) = o;
    }
}

// ---------------------------------------------------------------------------
extern "C" void kernel_launch(void* const* d_in, const int* in_sizes, int n_in,
                              void* d_out, int out_size, void* d_ws, size_t ws_size,
                              hipStream_t stream)
{
    const float* x  = (const float*)d_in[0];
    const float* wq = (const float*)d_in[1];
    const float* bq = (const float*)d_in[2];
    const float* wk = (const float*)d_in[3];
    const float* bk = (const float*)d_in[4];
    const float* wv = (const float*)d_in[5];
    const float* bv = (const float*)d_in[6];
    const float* wo = (const float*)d_in[7];
    const float* bo = (const float*)d_in[8];
    float* out = (float*)d_out;
    float* ws  = (float*)d_ws;

    const size_t NN = (size_t)MROWS * EMBED;
    float* Qb = ws;
    float* Kb = ws + NN;
    float* Vb = ws + 2 * NN;
    float* Ab = ws + 3 * NN;

    const dim3 blk(256);
    const dim3 gg(MROWS / GT, EMBED / GT);   // 64 x 8
    gemm_bt_bias<<<gg, blk, 0, stream>>>(x, wq, bq, Qb, MROWS, EMBED, EMBED);
    gemm_bt_bias<<<gg, blk, 0, stream>>>(x, wk, bk, Kb, MROWS, EMBED, EMBED);
    gemm_bt_bias<<<gg, blk, 0, stream>>>(x, wv, bv, Vb, MROWS, EMBED, EMBED);

    const dim3 ga(SEQL / QT, BATCH * HEADS); // 16 x 128
    attn_fwd<<<ga, blk, 0, stream>>>(Qb, Kb, Vb, Ab);

    gemm_bt_bias<<<gg, blk, 0, stream>>>(Ab, wo, bo, out, MROWS, EMBED, EMBED);
}

// Round 4
// 513.284 us; speedup vs baseline: 2.7173x; 2.7173x over previous
//
#include <hip/hip_runtime.h>
#include <hip/hip_bf16.h>
#include <math.h>

#define EMBED 1024
#define HEADS 16
#define HDIM 64
#define BATCH 8
#define SEQL 1024
#define MROWS (BATCH * SEQL)   // 8192
#define KK2 (2 * EMBED)        // 2048 (hi|lo concat K storage)

typedef __bf16 bf16x8 __attribute__((ext_vector_type(8)));
typedef float  f32x4  __attribute__((ext_vector_type(4)));

__device__ __forceinline__ void gload_lds16(const void* g, void* l) {
    __builtin_amdgcn_global_load_lds(
        (__attribute__((address_space(1))) void*)g,
        (__attribute__((address_space(3))) void*)l, 16, 0, 0);
}

__device__ __forceinline__ void split_bf16(float f, __bf16& hi, __bf16& lo) {
    hi = (__bf16)f;
    lo = (__bf16)(f - (float)hi);
}

// ---------------------------------------------------------------------------
// cvt_split: fp32 [nrows][1024] -> bf16 [nrows][2048] as [hi(1024) | lo(1024)].
// ---------------------------------------------------------------------------
__global__ __launch_bounds__(256)
void cvt_split(const float* __restrict__ in, __bf16* __restrict__ out)
{
    const int r = blockIdx.x;
    const int c4 = threadIdx.x * 4;
    const float4 v = *reinterpret_cast<const float4*>(&in[(size_t)r * EMBED + c4]);
    union { __bf16 h[4]; short4 s; } uh, ul;
    split_bf16(v.x, uh.h[0], ul.h[0]);
    split_bf16(v.y, uh.h[1], ul.h[1]);
    split_bf16(v.z, uh.h[2], ul.h[2]);
    split_bf16(v.w, uh.h[3], ul.h[3]);
    __bf16* ro = out + (size_t)r * KK2;
    *reinterpret_cast<short4*>(ro + c4)         = uh.s;
    *reinterpret_cast<short4*>(ro + EMBED + c4) = ul.s;
}

// ---------------------------------------------------------------------------
// GEMM: C[M,N] = A[M,1024] @ B[N,1024]^T (+bias), split-fp32 via bf16 MFMA.
// A,B stored [hi(1024)|lo(1024)]. 48 K-steps of 64: steps 0-15 hi*hi,
// 16-31 lo*hi, 32-47 hi*lo  =>  3-term bf16x3 accuracy (residual ~2^-17).
// 128x128 tile, 4 waves (each 64x64 via 4x4 16x16 frags), global_load_lds.
// MODE 0: fp32 out [M][1024] + bias
// MODE 1: (acc+bias)*scale -> split hi/lo bf16 -> [b][h][s][128] (Q2/K2)
// MODE 2: acc+bias -> split hi/lo bf16 -> [b][h][d][2048] (VT, keys hi|lo)
// ---------------------------------------------------------------------------
#define GN EMBED
#define BK 64

template <int MODE>
__global__ __launch_bounds__(256)
void gemm_mfma(const __bf16* __restrict__ A, const __bf16* __restrict__ B,
               const float* __restrict__ bias, void* __restrict__ Cout,
               float scale)
{
    __shared__ __align__(16) __bf16 As[128][BK];   // 16 KB, linear
    __shared__ __align__(16) __bf16 Bs[128][BK];   // 16 KB, linear

    const int tid = threadIdx.x;
    const int w    = tid >> 6;
    const int lane = tid & 63;
    const int lr = lane & 15;
    const int lh = lane >> 4;
    const int wr = w >> 1;       // 0..1
    const int wc = w & 1;        // 0..1
    const int bm = blockIdx.x * 128;
    const int bn = blockIdx.y * 128;

    f32x4 acc[4][4];
    #pragma unroll
    for (int m = 0; m < 4; ++m)
        #pragma unroll
        for (int n = 0; n < 4; ++n) acc[m][n] = (f32x4){0.f, 0.f, 0.f, 0.f};

    for (int step = 0; step < 48; ++step) {
        const int ph    = step >> 4;            // 0:hi*hi 1:lo*hi 2:hi*lo
        const int kbase = (step & 15) * BK;
        const int ka = kbase + ((ph == 1) ? EMBED : 0);
        const int kb = kbase + ((ph == 2) ? EMBED : 0);

        #pragma unroll
        for (int i = 0; i < 4; ++i) {
            const int idx = tid + i * 256;          // 0..1023
            const int r   = idx >> 3;               // 0..127
            const int kc  = (idx & 7) * 8;          // 0..56
            gload_lds16(A + (size_t)(bm + r) * KK2 + ka + kc,
                        (char*)As + i * 4096 + w * 1024);
            gload_lds16(B + (size_t)(bn + r) * KK2 + kb + kc,
                        (char*)Bs + i * 4096 + w * 1024);
        }
        __syncthreads();

        #pragma unroll
        for (int kk = 0; kk < 2; ++kk) {
            bf16x8 af[4], bfr[4];
            #pragma unroll
            for (int m = 0; m < 4; ++m)
                af[m] = *reinterpret_cast<const bf16x8*>(
                    &As[wr * 64 + m * 16 + lr][kk * 32 + lh * 8]);
            #pragma unroll
            for (int n = 0; n < 4; ++n)
                bfr[n] = *reinterpret_cast<const bf16x8*>(
                    &Bs[wc * 64 + n * 16 + lr][kk * 32 + lh * 8]);
            #pragma unroll
            for (int m = 0; m < 4; ++m)
                #pragma unroll
                for (int n = 0; n < 4; ++n)
                    acc[m][n] = __builtin_amdgcn_mfma_f32_16x16x32_bf16(
                        af[m], bfr[n], acc[m][n], 0, 0, 0);
        }
        __syncthreads();
    }

    // epilogue: C-frag (row = lh*4+j, col = lr) per 16x16 block
    #pragma unroll
    for (int m = 0; m < 4; ++m) {
        #pragma unroll
        for (int n = 0; n < 4; ++n) {
            const int col = bn + wc * 64 + n * 16 + lr;
            const float bv = bias[col];
            #pragma unroll
            for (int j = 0; j < 4; ++j) {
                const int row = bm + wr * 64 + m * 16 + lh * 4 + j;
                const float f = acc[m][n][j] + bv;
                if (MODE == 0) {
                    ((float*)Cout)[(size_t)row * GN + col] = f;
                } else {
                    const int b = row >> 10, s = row & 1023;
                    const int h = col >> 6,  d = col & 63;
                    __bf16 hi, lo;
                    if (MODE == 1) {
                        split_bf16(f * scale, hi, lo);
                        __bf16* q2 = (__bf16*)Cout +
                            (((size_t)(b * HEADS + h) * SEQL + s) * 128 + d);
                        q2[0]  = hi;
                        q2[64] = lo;
                    } else {
                        split_bf16(f, hi, lo);
                        __bf16* vp = (__bf16*)Cout +
                            (((size_t)(b * HEADS + h) * HDIM + d) * 2048 + s);
                        vp[0]    = hi;
                        vp[1024] = lo;
                    }
                }
            }
        }
    }
}

// ---------------------------------------------------------------------------
// Flash attention, bf16 MFMA, split-fp32 scores (3-term) and split V.
// Block = (q-tile of 64) x (b,h); 4 waves, each owns 16 q rows.
// Q2/K2: [b][h][s][128] hi|lo.  VT: [b][h][d][2048] keys hi|lo.
// LDS tiles XOR-swizzled (pre-swizzled global source for global_load_lds).
// Output written directly as hi|lo bf16 A-operand of the final GEMM.
// ---------------------------------------------------------------------------
#define KT 64

__global__ __launch_bounds__(256)
void attn_mfma(const __bf16* __restrict__ Q2, const __bf16* __restrict__ K2,
               const __bf16* __restrict__ VT, __bf16* __restrict__ Ab2)
{
    __shared__ __align__(16) char QsB[16384];    // [64 q][128 d'] swizzled
    __shared__ __align__(16) char KsB[16384];    // [64 k][128 d'] swizzled
    __shared__ __align__(16) char VsB[16384];    // [64 d][128 s'] swizzled (hi|lo)
    __shared__ __align__(16) char PsB[4][2048];  // per-wave [16 q][64 k] swizzled

    const int tid  = threadIdx.x;
    const int w    = tid >> 6;
    const int lane = tid & 63;
    const int lr = lane & 15;
    const int lh = lane >> 4;
    const int qt0 = blockIdx.x * 64;
    const int bh  = blockIdx.y;
    const int b   = bh >> 4;

    const __bf16* Qg = Q2 + (size_t)bh * SEQL * 128;
    const __bf16* Kg = K2 + (size_t)bh * SEQL * 128;
    const __bf16* Vg = VT + (size_t)bh * HDIM * 2048;

    // stage Q tile once (rows = 256 B, 16 lanes/row); pre-swizzled source col
    #pragma unroll
    for (int i = 0; i < 4; ++i) {
        const int idx = tid + i * 256;
        const int r   = idx >> 4;
        const int cb  = ((idx & 15) * 16) ^ ((r & 7) << 4);
        gload_lds16(Qg + (size_t)(qt0 + r) * 128 + cb / 2,
                    QsB + i * 4096 + w * 1024);
    }

    f32x4 oacc[4];
    #pragma unroll
    for (int nd = 0; nd < 4; ++nd) oacc[nd] = (f32x4){0.f, 0.f, 0.f, 0.f};
    float m_run[4], l_run[4];
    #pragma unroll
    for (int j = 0; j < 4; ++j) { m_run[j] = -1e30f; l_run[j] = 0.f; }

    bf16x8 qf[4];

    for (int kt = 0; kt < SEQL / KT; ++kt) {
        // stage K tile [64][128 d'] and V tile [64 d][128 s' (hi|lo)]
        #pragma unroll
        for (int i = 0; i < 4; ++i) {
            const int idx = tid + i * 256;
            const int r   = idx >> 4;
            const int cb  = ((idx & 15) * 16) ^ ((r & 7) << 4);
            gload_lds16(Kg + (size_t)(kt * KT + r) * 128 + cb / 2,
                        KsB + i * 4096 + w * 1024);
        }
        #pragma unroll
        for (int i = 0; i < 4; ++i) {
            const int idx = tid + i * 256;
            const int r   = idx >> 4;                      // d row
            const int cb  = ((idx & 15) * 16) ^ ((r & 7) << 4);
            const int ce  = cb / 2;                        // 0..127, 8-aligned
            const size_t goff = (size_t)r * 2048 +
                ((ce < 64) ? (kt * KT + ce) : (1024 + kt * KT + ce - 64));
            gload_lds16(Vg + goff, VsB + i * 4096 + w * 1024);
        }
        __syncthreads();

        if (kt == 0) {
            #pragma unroll
            for (int kk = 0; kk < 4; ++kk) {
                const int row = w * 16 + lr;
                const int off = row * 256 + ((kk * 64 + lh * 16) ^ ((row & 7) << 4));
                qf[kk] = *reinterpret_cast<const bf16x8*>(QsB + off);
            }
        }

        // QK^T, 3-term: qhi*khi + qlo*khi + qhi*klo  (6 MFMA per 16x16 block)
        f32x4 sc[4];
        #pragma unroll
        for (int n = 0; n < 4; ++n) sc[n] = (f32x4){0.f, 0.f, 0.f, 0.f};
        #pragma unroll
        for (int n = 0; n < 4; ++n) {
            const int row = n * 16 + lr;
            bf16x8 kf[4];
            #pragma unroll
            for (int kk = 0; kk < 4; ++kk) {
                const int off = row * 256 + ((kk * 64 + lh * 16) ^ ((row & 7) << 4));
                kf[kk] = *reinterpret_cast<const bf16x8*>(KsB + off);
            }
            sc[n] = __builtin_amdgcn_mfma_f32_16x16x32_bf16(qf[0], kf[0], sc[n], 0, 0, 0);
            sc[n] = __builtin_amdgcn_mfma_f32_16x16x32_bf16(qf[1], kf[1], sc[n], 0, 0, 0);
            sc[n] = __builtin_amdgcn_mfma_f32_16x16x32_bf16(qf[2], kf[0], sc[n], 0, 0, 0);
            sc[n] = __builtin_amdgcn_mfma_f32_16x16x32_bf16(qf[3], kf[1], sc[n], 0, 0, 0);
            sc[n] = __builtin_amdgcn_mfma_f32_16x16x32_bf16(qf[0], kf[2], sc[n], 0, 0, 0);
            sc[n] = __builtin_amdgcn_mfma_f32_16x16x32_bf16(qf[1], kf[3], sc[n], 0, 0, 0);
        }

        // online softmax (q-row = w*16 + lh*4 + j; reduce across 16-lane group)
        float p[4][4], alpha[4];
        #pragma unroll
        for (int j = 0; j < 4; ++j) {
            float pm = fmaxf(fmaxf(sc[0][j], sc[1][j]), fmaxf(sc[2][j], sc[3][j]));
            #pragma unroll
            for (int off = 1; off < 16; off <<= 1)
                pm = fmaxf(pm, __shfl_xor(pm, off));
            const float mn = fmaxf(m_run[j], pm);
            alpha[j] = __expf(m_run[j] - mn);
            m_run[j] = mn;
            float ps = 0.f;
            #pragma unroll
            for (int n = 0; n < 4; ++n) { p[n][j] = __expf(sc[n][j] - mn); ps += p[n][j]; }
            #pragma unroll
            for (int off = 1; off < 16; off <<= 1)
                ps += __shfl_xor(ps, off);
            l_run[j] = l_run[j] * alpha[j] + ps;
        }
        #pragma unroll
        for (int nd = 0; nd < 4; ++nd)
            #pragma unroll
            for (int j = 0; j < 4; ++j) oacc[nd][j] *= alpha[j];

        // P -> bf16 -> per-wave LDS (swizzled), then PV (P*Vhi + P*Vlo)
        char* Pw = PsB[w];
        #pragma unroll
        for (int j = 0; j < 4; ++j) {
            const int row = lh * 4 + j;
            #pragma unroll
            for (int n = 0; n < 4; ++n) {
                const int cb = ((n * 16 + lr) * 2) ^ ((row & 7) << 4);
                *reinterpret_cast<__bf16*>(Pw + row * 128 + cb) = (__bf16)p[n][j];
            }
        }
        #pragma unroll
        for (int ks = 0; ks < 2; ++ks) {
            const int poff = lr * 128 + ((ks * 64 + lh * 16) ^ ((lr & 7) << 4));
            const bf16x8 pf = *reinterpret_cast<const bf16x8*>(Pw + poff);
            #pragma unroll
            for (int vh = 0; vh < 2; ++vh) {
                #pragma unroll
                for (int nd = 0; nd < 4; ++nd) {
                    const int row = nd * 16 + lr;
                    const int off = row * 256 +
                        ((vh * 128 + ks * 64 + lh * 16) ^ ((row & 7) << 4));
                    const bf16x8 vf = *reinterpret_cast<const bf16x8*>(VsB + off);
                    oacc[nd] = __builtin_amdgcn_mfma_f32_16x16x32_bf16(
                        pf, vf, oacc[nd], 0, 0, 0);
                }
            }
        }
        __syncthreads();   // all waves done with Ks/Vs before next stage
    }

    // epilogue: O = acc/l, write hi|lo bf16 into Ab2 [8192][2048]
    const int h = bh & (HEADS - 1);
    #pragma unroll
    for (int j = 0; j < 4; ++j) {
        const float rl = 1.f / l_run[j];
        const size_t gm = (size_t)b * SEQL + qt0 + w * 16 + lh * 4 + j;
        #pragma unroll
        for (int nd = 0; nd < 4; ++nd) {
            const int e = h * 64 + nd * 16 + lr;
            __bf16 hi, lo;
            split_bf16(oacc[nd][j] * rl, hi, lo);
            Ab2[gm * KK2 + e]         = hi;
            Ab2[gm * KK2 + EMBED + e] = lo;
        }
    }
}

// ---------------------------------------------------------------------------
extern "C" void kernel_launch(void* const* d_in, const int* in_sizes, int n_in,
                              void* d_out, int out_size, void* d_ws, size_t ws_size,
                              hipStream_t stream)
{
    const float* x  = (const float*)d_in[0];
    const float* wq = (const float*)d_in[1];
    const float* bq = (const float*)d_in[2];
    const float* wk = (const float*)d_in[3];
    const float* bk = (const float*)d_in[4];
    const float* wv = (const float*)d_in[5];
    const float* bv = (const float*)d_in[6];
    const float* wo = (const float*)d_in[7];
    const float* bo = (const float*)d_in[8];
    float* out = (float*)d_out;

    // workspace layout (Ab2 aliases x2: x2 dead after the V GEMM)
    char* p = (char*)d_ws;
    __bf16* x2  = (__bf16*)p;  p += (size_t)MROWS * KK2 * 2;              // 33.5 MB
    __bf16* wq2 = (__bf16*)p;  p += (size_t)EMBED * KK2 * 2;              //  4.2 MB
    __bf16* wk2 = (__bf16*)p;  p += (size_t)EMBED * KK2 * 2;
    __bf16* wv2 = (__bf16*)p;  p += (size_t)EMBED * KK2 * 2;
    __bf16* wo2 = (__bf16*)p;  p += (size_t)EMBED * KK2 * 2;
    __bf16* Q2  = (__bf16*)p;  p += (size_t)BATCH * HEADS * SEQL * 128 * 2; // 33.5 MB
    __bf16* K2  = (__bf16*)p;  p += (size_t)BATCH * HEADS * SEQL * 128 * 2; // 33.5 MB
    __bf16* VT  = (__bf16*)p;  p += (size_t)BATCH * HEADS * HDIM * 2048 * 2;// 33.5 MB
    __bf16* Ab2 = x2;

    const dim3 blk(256);
    cvt_split<<<dim3(MROWS), blk, 0, stream>>>(x,  x2);
    cvt_split<<<dim3(EMBED), blk, 0, stream>>>(wq, wq2);
    cvt_split<<<dim3(EMBED), blk, 0, stream>>>(wk, wk2);
    cvt_split<<<dim3(EMBED), blk, 0, stream>>>(wv, wv2);
    cvt_split<<<dim3(EMBED), blk, 0, stream>>>(wo, wo2);

    const dim3 gg(MROWS / 128, EMBED / 128);   // 64 x 8
    const float scale = 0.125f;                // 1/sqrt(HDIM), folded into Q
    gemm_mfma<1><<<gg, blk, 0, stream>>>(x2, wq2, bq, Q2, scale);
    gemm_mfma<1><<<gg, blk, 0, stream>>>(x2, wk2, bk, K2, 1.0f);
    gemm_mfma<2><<<gg, blk, 0, stream>>>(x2, wv2, bv, VT, 1.0f);

    attn_mfma<<<dim3(SEQL / 64, BATCH * HEADS), blk, 0, stream>>>(Q2, K2, VT, Ab2);

    gemm_mfma<0><<<gg, blk, 0, stream>>>(Ab2, wo2, bo, out, 1.0f);
}

// Round 5
// 461.144 us; speedup vs baseline: 3.0245x; 1.1131x over previous
//
#include <hip/hip_runtime.h>
#include <hip/hip_bf16.h>
#include <math.h>

#define EMBED 1024
#define HEADS 16
#define HDIM 64
#define BATCH 8
#define SEQL 1024
#define MROWS (BATCH * SEQL)   // 8192
#define KK2 (2 * EMBED)        // 2048 (hi|lo concat K storage)

typedef __bf16 bf16x8 __attribute__((ext_vector_type(8)));
typedef float  f32x4  __attribute__((ext_vector_type(4)));

__device__ __forceinline__ void gload_lds16(const void* g, void* l) {
    __builtin_amdgcn_global_load_lds(
        (__attribute__((address_space(1))) void*)g,
        (__attribute__((address_space(3))) void*)l, 16, 0, 0);
}

__device__ __forceinline__ void split_bf16(float f, __bf16& hi, __bf16& lo) {
    hi = (__bf16)f;
    lo = (__bf16)(f - (float)hi);
}

__device__ __forceinline__ unsigned pack_bf16(float a, float b) {
    union { __bf16 h[2]; unsigned u; } t;
    t.h[0] = (__bf16)a; t.h[1] = (__bf16)b;
    return t.u;
}

// ---------------------------------------------------------------------------
// cvt_split: fp32 [nrows][1024] -> bf16 [nrows][2048] as [hi(1024) | lo(1024)].
// ---------------------------------------------------------------------------
__global__ __launch_bounds__(256)
void cvt_split(const float* __restrict__ in, __bf16* __restrict__ out)
{
    const int r = blockIdx.x;
    const int c4 = threadIdx.x * 4;
    const float4 v = *reinterpret_cast<const float4*>(&in[(size_t)r * EMBED + c4]);
    union { __bf16 h[4]; short4 s; } uh, ul;
    split_bf16(v.x, uh.h[0], ul.h[0]);
    split_bf16(v.y, uh.h[1], ul.h[1]);
    split_bf16(v.z, uh.h[2], ul.h[2]);
    split_bf16(v.w, uh.h[3], ul.h[3]);
    __bf16* ro = out + (size_t)r * KK2;
    *reinterpret_cast<short4*>(ro + c4)         = uh.s;
    *reinterpret_cast<short4*>(ro + EMBED + c4) = ul.s;
}

// ---------------------------------------------------------------------------
// GEMM: C[M,N] = A[M,1024] @ B[N,1024]^T (+bias), split-fp32 via bf16 MFMA.
// A,B stored [hi(1024)|lo(1024)]. 48 K-steps of 64: hi*hi, lo*hi, hi*lo.
// 128x128 tile, 4 waves, global_load_lds. (m97 structure)
// MODE 0: fp32 out [M][1024] + bias
// MODE 1: (acc+bias)*scale -> split hi/lo bf16 -> [b][h][s][128] (Q2/K2)
// MODE 2: acc+bias -> split hi/lo bf16 -> [b][h][d][2048] (VT, keys hi|lo)
// ---------------------------------------------------------------------------
#define GN EMBED
#define BK 64

template <int MODE>
__global__ __launch_bounds__(256)
void gemm_mfma(const __bf16* __restrict__ A, const __bf16* __restrict__ B,
               const float* __restrict__ bias, void* __restrict__ Cout,
               float scale)
{
    __shared__ __align__(16) __bf16 As[128][BK];   // 16 KB, linear
    __shared__ __align__(16) __bf16 Bs[128][BK];   // 16 KB, linear

    const int tid = threadIdx.x;
    const int w    = tid >> 6;
    const int lane = tid & 63;
    const int lr = lane & 15;
    const int lh = lane >> 4;
    const int wr = w >> 1;       // 0..1
    const int wc = w & 1;        // 0..1
    const int bm = blockIdx.x * 128;
    const int bn = blockIdx.y * 128;

    f32x4 acc[4][4];
    #pragma unroll
    for (int m = 0; m < 4; ++m)
        #pragma unroll
        for (int n = 0; n < 4; ++n) acc[m][n] = (f32x4){0.f, 0.f, 0.f, 0.f};

    for (int step = 0; step < 48; ++step) {
        const int ph    = step >> 4;            // 0:hi*hi 1:lo*hi 2:hi*lo
        const int kbase = (step & 15) * BK;
        const int ka = kbase + ((ph == 1) ? EMBED : 0);
        const int kb = kbase + ((ph == 2) ? EMBED : 0);

        #pragma unroll
        for (int i = 0; i < 4; ++i) {
            const int idx = tid + i * 256;          // 0..1023
            const int r   = idx >> 3;               // 0..127
            const int kc  = (idx & 7) * 8;          // 0..56
            gload_lds16(A + (size_t)(bm + r) * KK2 + ka + kc,
                        (char*)As + i * 4096 + w * 1024);
            gload_lds16(B + (size_t)(bn + r) * KK2 + kb + kc,
                        (char*)Bs + i * 4096 + w * 1024);
        }
        __syncthreads();

        #pragma unroll
        for (int kk = 0; kk < 2; ++kk) {
            bf16x8 af[4], bfr[4];
            #pragma unroll
            for (int m = 0; m < 4; ++m)
                af[m] = *reinterpret_cast<const bf16x8*>(
                    &As[wr * 64 + m * 16 + lr][kk * 32 + lh * 8]);
            #pragma unroll
            for (int n = 0; n < 4; ++n)
                bfr[n] = *reinterpret_cast<const bf16x8*>(
                    &Bs[wc * 64 + n * 16 + lr][kk * 32 + lh * 8]);
            #pragma unroll
            for (int m = 0; m < 4; ++m)
                #pragma unroll
                for (int n = 0; n < 4; ++n)
                    acc[m][n] = __builtin_amdgcn_mfma_f32_16x16x32_bf16(
                        af[m], bfr[n], acc[m][n], 0, 0, 0);
        }
        __syncthreads();
    }

    #pragma unroll
    for (int m = 0; m < 4; ++m) {
        #pragma unroll
        for (int n = 0; n < 4; ++n) {
            const int col = bn + wc * 64 + n * 16 + lr;
            const float bv = bias[col];
            #pragma unroll
            for (int j = 0; j < 4; ++j) {
                const int row = bm + wr * 64 + m * 16 + lh * 4 + j;
                const float f = acc[m][n][j] + bv;
                if (MODE == 0) {
                    ((float*)Cout)[(size_t)row * GN + col] = f;
                } else {
                    const int b = row >> 10, s = row & 1023;
                    const int h = col >> 6,  d = col & 63;
                    __bf16 hi, lo;
                    if (MODE == 1) {
                        split_bf16(f * scale, hi, lo);
                        __bf16* q2 = (__bf16*)Cout +
                            (((size_t)(b * HEADS + h) * SEQL + s) * 128 + d);
                        q2[0]  = hi;
                        q2[64] = lo;
                    } else {
                        split_bf16(f, hi, lo);
                        __bf16* vp = (__bf16*)Cout +
                            (((size_t)(b * HEADS + h) * HDIM + d) * 2048 + s);
                        vp[0]    = hi;
                        vp[1024] = lo;
                    }
                }
            }
        }
    }
}

// ---------------------------------------------------------------------------
// Flash attention v2: swapped QK^T (mfma(K,Q)) so each lane owns ONE q row's
// scores -> softmax = 15 in-lane ops + 2 shfls; P stays in registers and is
// redistributed into PV A-fragments via bpermute (no P LDS). Q fragments
// loaded directly from global (no Q LDS). LDS = K tile 16KB + V tile 16KB.
// Q2/K2: [b][h][s][128] hi|lo.  VT: [b][h][d][2048] keys hi|lo.
// ---------------------------------------------------------------------------
#define KT 64

__global__ __launch_bounds__(256, 4)
void attn_mfma(const __bf16* __restrict__ Q2, const __bf16* __restrict__ K2,
               const __bf16* __restrict__ VT, __bf16* __restrict__ Ab2)
{
    __shared__ __align__(16) char KsB[16384];    // [64 k][128 d'] swizzled
    __shared__ __align__(16) char VsB[16384];    // [64 d][128 s'(hi|lo)] swizzled

    const int tid  = threadIdx.x;
    const int w    = tid >> 6;
    const int lane = tid & 63;
    const int lr = lane & 15;
    const int lh = lane >> 4;
    const int qt0 = blockIdx.x * 64;
    const int bh  = blockIdx.y;
    const int b   = bh >> 4;

    const __bf16* Qg = Q2 + (size_t)bh * SEQL * 128;
    const __bf16* Kg = K2 + (size_t)bh * SEQL * 128;
    const __bf16* Vg = VT + (size_t)bh * HDIM * 2048;

    // Q fragments straight from global: row = qt0 + w*16 + lr, d' = kk*32+lh*8
    bf16x8 qf[4];
    {
        const __bf16* qrow = Qg + (size_t)(qt0 + w * 16 + lr) * 128 + lh * 8;
        #pragma unroll
        for (int kk = 0; kk < 4; ++kk)
            qf[kk] = *reinterpret_cast<const bf16x8*>(qrow + kk * 32);
    }

    f32x4 oacc[4];                       // O[q=4lh+j][d=nd*16+lr]
    #pragma unroll
    for (int nd = 0; nd < 4; ++nd) oacc[nd] = (f32x4){0.f, 0.f, 0.f, 0.f};
    float m_run = -1e30f, l_run = 0.f;   // for q row = lr (this wave)

    const int s0 = lr + 32 * (lh & 1);   // bpermute source lanes
    const int s1 = s0 + 16;
    const bool hi_n = (lh >> 1) != 0;

    for (int kt = 0; kt < SEQL / KT; ++kt) {
        // stage K tile [64][128 d'] and V tile [64 d][128 s'(hi|lo)], swizzled src
        #pragma unroll
        for (int i = 0; i < 4; ++i) {
            const int idx = tid + i * 256;
            const int r   = idx >> 4;
            const int cb  = ((idx & 15) * 16) ^ ((r & 7) << 4);
            gload_lds16(Kg + (size_t)(kt * KT + r) * 128 + cb / 2,
                        KsB + i * 4096 + w * 1024);
        }
        #pragma unroll
        for (int i = 0; i < 4; ++i) {
            const int idx = tid + i * 256;
            const int r   = idx >> 4;                      // d row
            const int cb  = ((idx & 15) * 16) ^ ((r & 7) << 4);
            const int ce  = cb / 2;                        // 0..127, 8-aligned
            const size_t goff = (size_t)r * 2048 +
                ((ce < 64) ? (kt * KT + ce) : (1024 + kt * KT + ce - 64));
            gload_lds16(Vg + goff, VsB + i * 4096 + w * 1024);
        }
        __syncthreads();

        // QK^T swapped: sc[n][reg] = S[k = 16n+4lh+reg][q = lr], 3-term
        f32x4 sc[4];
        #pragma unroll
        for (int n = 0; n < 4; ++n) {
            const int row = n * 16 + lr;
            bf16x8 kf[4];
            #pragma unroll
            for (int kk = 0; kk < 4; ++kk) {
                const int off = row * 256 + ((kk * 64 + lh * 16) ^ ((row & 7) << 4));
                kf[kk] = *reinterpret_cast<const bf16x8*>(KsB + off);
            }
            f32x4 s = (f32x4){0.f, 0.f, 0.f, 0.f};
            s = __builtin_amdgcn_mfma_f32_16x16x32_bf16(kf[0], qf[0], s, 0, 0, 0);
            s = __builtin_amdgcn_mfma_f32_16x16x32_bf16(kf[1], qf[1], s, 0, 0, 0);
            s = __builtin_amdgcn_mfma_f32_16x16x32_bf16(kf[0], qf[2], s, 0, 0, 0);
            s = __builtin_amdgcn_mfma_f32_16x16x32_bf16(kf[1], qf[3], s, 0, 0, 0);
            s = __builtin_amdgcn_mfma_f32_16x16x32_bf16(kf[2], qf[0], s, 0, 0, 0);
            s = __builtin_amdgcn_mfma_f32_16x16x32_bf16(kf[3], qf[1], s, 0, 0, 0);
            sc[n] = s;
        }

        // online softmax for q = lr (16 values in-lane, combine 4 lh-groups)
        float pm = sc[0][0];
        #pragma unroll
        for (int n = 0; n < 4; ++n)
            #pragma unroll
            for (int j = 0; j < 4; ++j) pm = fmaxf(pm, sc[n][j]);
        pm = fmaxf(pm, __shfl_xor(pm, 16));
        pm = fmaxf(pm, __shfl_xor(pm, 32));
        const float mn    = fmaxf(m_run, pm);
        const float alpha = __expf(m_run - mn);
        m_run = mn;

        float p[4][4], ps = 0.f;
        #pragma unroll
        for (int n = 0; n < 4; ++n)
            #pragma unroll
            for (int j = 0; j < 4; ++j) {
                p[n][j] = __expf(sc[n][j] - mn);
                ps += p[n][j];
            }
        ps += __shfl_xor(ps, 16);
        ps += __shfl_xor(ps, 32);
        l_run = l_run * alpha + ps;

        // pack P to bf16 dwords: pk[n][0]=(reg0,reg1), pk[n][1]=(reg2,reg3)
        unsigned pk[4][2];
        #pragma unroll
        for (int n = 0; n < 4; ++n) {
            pk[n][0] = pack_bf16(p[n][0], p[n][1]);
            pk[n][1] = pack_bf16(p[n][2], p[n][3]);
        }

        // redistribute into A-frags pa[ks] = P[q=lr][k = 32ks+8lh .. +7]
        unsigned pa[2][4];
        #pragma unroll
        for (int ks = 0; ks < 2; ++ks) {
            const unsigned a0 = __shfl(pk[2 * ks][0],     s0);
            const unsigned b0 = __shfl(pk[2 * ks + 1][0], s0);
            const unsigned a1 = __shfl(pk[2 * ks][1],     s0);
            const unsigned b1 = __shfl(pk[2 * ks + 1][1], s0);
            const unsigned a2 = __shfl(pk[2 * ks][0],     s1);
            const unsigned b2 = __shfl(pk[2 * ks + 1][0], s1);
            const unsigned a3 = __shfl(pk[2 * ks][1],     s1);
            const unsigned b3 = __shfl(pk[2 * ks + 1][1], s1);
            pa[ks][0] = hi_n ? b0 : a0;
            pa[ks][1] = hi_n ? b1 : a1;
            pa[ks][2] = hi_n ? b2 : a2;
            pa[ks][3] = hi_n ? b3 : a3;
        }

        // rescale oacc rows (q = 4lh+j) by that row's alpha
        float av[4];
        #pragma unroll
        for (int j = 0; j < 4; ++j)
            av[j] = __shfl(alpha, (lane & 48) | ((4 * lh + j) & 15));
        #pragma unroll
        for (int nd = 0; nd < 4; ++nd)
            #pragma unroll
            for (int j = 0; j < 4; ++j) oacc[nd][j] *= av[j];

        // PV: O += P * (Vhi + Vlo)
        #pragma unroll
        for (int ks = 0; ks < 2; ++ks) {
            const bf16x8 pf = *reinterpret_cast<const bf16x8*>(&pa[ks][0]);
            #pragma unroll
            for (int vh = 0; vh < 2; ++vh) {
                #pragma unroll
                for (int nd = 0; nd < 4; ++nd) {
                    const int row = nd * 16 + lr;
                    const int off = row * 256 +
                        ((vh * 128 + ks * 64 + lh * 16) ^ ((row & 7) << 4));
                    const bf16x8 vf = *reinterpret_cast<const bf16x8*>(VsB + off);
                    oacc[nd] = __builtin_amdgcn_mfma_f32_16x16x32_bf16(
                        pf, vf, oacc[nd], 0, 0, 0);
                }
            }
        }
        __syncthreads();   // all waves done with Ks/Vs before next stage
    }

    // epilogue: O = acc/l, write hi|lo bf16 into Ab2 [8192][2048]
    const int h = bh & (HEADS - 1);
    #pragma unroll
    for (int j = 0; j < 4; ++j) {
        const float lv = __shfl(l_run, (lane & 48) | ((4 * lh + j) & 15));
        const float rl = 1.f / lv;
        const size_t gm = (size_t)b * SEQL + qt0 + w * 16 + 4 * lh + j;
        #pragma unroll
        for (int nd = 0; nd < 4; ++nd) {
            const int e = h * 64 + nd * 16 + lr;
            __bf16 hi, lo;
            split_bf16(oacc[nd][j] * rl, hi, lo);
            Ab2[gm * KK2 + e]         = hi;
            Ab2[gm * KK2 + EMBED + e] = lo;
        }
    }
}

// ---------------------------------------------------------------------------
extern "C" void kernel_launch(void* const* d_in, const int* in_sizes, int n_in,
                              void* d_out, int out_size, void* d_ws, size_t ws_size,
                              hipStream_t stream)
{
    const float* x  = (const float*)d_in[0];
    const float* wq = (const float*)d_in[1];
    const float* bq = (const float*)d_in[2];
    const float* wk = (const float*)d_in[3];
    const float* bk = (const float*)d_in[4];
    const float* wv = (const float*)d_in[5];
    const float* bv = (const float*)d_in[6];
    const float* wo = (const float*)d_in[7];
    const float* bo = (const float*)d_in[8];
    float* out = (float*)d_out;

    // workspace layout (Ab2 aliases x2: x2 dead after the V GEMM)
    char* p = (char*)d_ws;
    __bf16* x2  = (__bf16*)p;  p += (size_t)MROWS * KK2 * 2;                // 33.5 MB
    __bf16* wq2 = (__bf16*)p;  p += (size_t)EMBED * KK2 * 2;                //  4.2 MB
    __bf16* wk2 = (__bf16*)p;  p += (size_t)EMBED * KK2 * 2;
    __bf16* wv2 = (__bf16*)p;  p += (size_t)EMBED * KK2 * 2;
    __bf16* wo2 = (__bf16*)p;  p += (size_t)EMBED * KK2 * 2;
    __bf16* Q2  = (__bf16*)p;  p += (size_t)BATCH * HEADS * SEQL * 128 * 2;   // 33.5 MB
    __bf16* K2  = (__bf16*)p;  p += (size_t)BATCH * HEADS * SEQL * 128 * 2;   // 33.5 MB
    __bf16* VT  = (__bf16*)p;  p += (size_t)BATCH * HEADS * HDIM * 2048 * 2;  // 33.5 MB
    __bf16* Ab2 = x2;

    const dim3 blk(256);
    cvt_split<<<dim3(MROWS), blk, 0, stream>>>(x,  x2);
    cvt_split<<<dim3(EMBED), blk, 0, stream>>>(wq, wq2);
    cvt_split<<<dim3(EMBED), blk, 0, stream>>>(wk, wk2);
    cvt_split<<<dim3(EMBED), blk, 0, stream>>>(wv, wv2);
    cvt_split<<<dim3(EMBED), blk, 0, stream>>>(wo, wo2);

    const dim3 gg(MROWS / 128, EMBED / 128);   // 64 x 8
    const float scale = 0.125f;                // 1/sqrt(HDIM), folded into Q
    gemm_mfma<1><<<gg, blk, 0, stream>>>(x2, wq2, bq, Q2, scale);
    gemm_mfma<1><<<gg, blk, 0, stream>>>(x2, wk2, bk, K2, 1.0f);
    gemm_mfma<2><<<gg, blk, 0, stream>>>(x2, wv2, bv, VT, 1.0f);

    attn_mfma<<<dim3(SEQL / 64, BATCH * HEADS), blk, 0, stream>>>(Q2, K2, VT, Ab2);

    gemm_mfma<0><<<gg, blk, 0, stream>>>(Ab2, wo2, bo, out, 1.0f);
}

// Round 6
// 322.678 us; speedup vs baseline: 4.3224x; 1.4291x over previous
//
#include <hip/hip_runtime.h>
#include <hip/hip_bf16.h>
#include <math.h>

#define EMBED 1024
#define HEADS 16
#define HDIM 64
#define BATCH 8
#define SEQL 1024
#define MROWS (BATCH * SEQL)   // 8192
#define KK2 (2 * EMBED)        // 2048 (hi|lo concat K storage)

typedef _Float16 f16x8 __attribute__((ext_vector_type(8)));
typedef float    f32x4 __attribute__((ext_vector_type(4)));

__device__ __forceinline__ void gload_lds16(const void* g, void* l) {
    __builtin_amdgcn_global_load_lds(
        (__attribute__((address_space(1))) void*)g,
        (__attribute__((address_space(3))) void*)l, 16, 0, 0);
}

__device__ __forceinline__ void split_f16(float f, _Float16& hi, _Float16& lo) {
    hi = (_Float16)f;
    lo = (_Float16)(f - (float)hi);
}

__device__ __forceinline__ unsigned pack_f16(float a, float b) {
    union { _Float16 h[2]; unsigned u; } t;
    t.h[0] = (_Float16)a; t.h[1] = (_Float16)b;
    return t.u;
}

// ---------------------------------------------------------------------------
// cvt_split: fp32 [nrows][1024] -> fp16 [nrows][2048] as [hi(1024) | lo(1024)].
// ---------------------------------------------------------------------------
__global__ __launch_bounds__(256)
void cvt_split(const float* __restrict__ in, _Float16* __restrict__ out)
{
    const int r = blockIdx.x;
    const int c4 = threadIdx.x * 4;
    const float4 v = *reinterpret_cast<const float4*>(&in[(size_t)r * EMBED + c4]);
    union { _Float16 h[4]; short4 s; } uh, ul;
    split_f16(v.x, uh.h[0], ul.h[0]);
    split_f16(v.y, uh.h[1], ul.h[1]);
    split_f16(v.z, uh.h[2], ul.h[2]);
    split_f16(v.w, uh.h[3], ul.h[3]);
    _Float16* ro = out + (size_t)r * KK2;
    *reinterpret_cast<short4*>(ro + c4)         = uh.s;
    *reinterpret_cast<short4*>(ro + EMBED + c4) = ul.s;
}

// ---------------------------------------------------------------------------
// GEMM: C[M,N] = A[M,1024] @ B[N,1024]^T (+bias), split-fp32 via fp16 MFMA.
// A,B stored [hi(1024)|lo(1024)] fp16. 32 K-steps of 64: Ahi*Bhi, Alo*Bhi
// (2-term; dropped A*Blo is 2^-11-relative). 128x128 tile, 4 waves,
// global_load_lds (m97 structure).
// MODE 0: fp32 out [M][1024] + bias
// MODE 1: (acc+bias)*scale -> split hi/lo fp16 -> [b][h][s][128] (Q2)
// MODE 2: acc+bias -> fp16 -> [b][h][d][1024] (VT, transposed)
// MODE 3: acc+bias -> fp16 -> [b][h][s][64]   (K2, hi only)
// ---------------------------------------------------------------------------
#define GN EMBED
#define BK 64

template <int MODE>
__global__ __launch_bounds__(256)
void gemm_mfma(const _Float16* __restrict__ A, const _Float16* __restrict__ B,
               const float* __restrict__ bias, void* __restrict__ Cout,
               float scale)
{
    __shared__ __align__(16) _Float16 As[128][BK];   // 16 KB, linear
    __shared__ __align__(16) _Float16 Bs[128][BK];   // 16 KB, linear

    const int tid = threadIdx.x;
    const int w    = tid >> 6;
    const int lane = tid & 63;
    const int lr = lane & 15;
    const int lh = lane >> 4;
    const int wr = w >> 1;       // 0..1
    const int wc = w & 1;        // 0..1
    const int bm = blockIdx.x * 128;
    const int bn = blockIdx.y * 128;

    f32x4 acc[4][4];
    #pragma unroll
    for (int m = 0; m < 4; ++m)
        #pragma unroll
        for (int n = 0; n < 4; ++n) acc[m][n] = (f32x4){0.f, 0.f, 0.f, 0.f};

    for (int step = 0; step < 32; ++step) {
        const int ph    = step >> 4;            // 0: hi*hi   1: lo*hi
        const int kbase = (step & 15) * BK;
        const int ka = kbase + (ph ? EMBED : 0);
        const int kb = kbase;

        #pragma unroll
        for (int i = 0; i < 4; ++i) {
            const int idx = tid + i * 256;          // 0..1023
            const int r   = idx >> 3;               // 0..127
            const int kc  = (idx & 7) * 8;          // 0..56
            gload_lds16(A + (size_t)(bm + r) * KK2 + ka + kc,
                        (char*)As + i * 4096 + w * 1024);
            gload_lds16(B + (size_t)(bn + r) * KK2 + kb + kc,
                        (char*)Bs + i * 4096 + w * 1024);
        }
        __syncthreads();

        #pragma unroll
        for (int kk = 0; kk < 2; ++kk) {
            f16x8 af[4], bfr[4];
            #pragma unroll
            for (int m = 0; m < 4; ++m)
                af[m] = *reinterpret_cast<const f16x8*>(
                    &As[wr * 64 + m * 16 + lr][kk * 32 + lh * 8]);
            #pragma unroll
            for (int n = 0; n < 4; ++n)
                bfr[n] = *reinterpret_cast<const f16x8*>(
                    &Bs[wc * 64 + n * 16 + lr][kk * 32 + lh * 8]);
            #pragma unroll
            for (int m = 0; m < 4; ++m)
                #pragma unroll
                for (int n = 0; n < 4; ++n)
                    acc[m][n] = __builtin_amdgcn_mfma_f32_16x16x32_f16(
                        af[m], bfr[n], acc[m][n], 0, 0, 0);
        }
        __syncthreads();
    }

    #pragma unroll
    for (int m = 0; m < 4; ++m) {
        #pragma unroll
        for (int n = 0; n < 4; ++n) {
            const int col = bn + wc * 64 + n * 16 + lr;
            const float bv = bias[col];
            #pragma unroll
            for (int j = 0; j < 4; ++j) {
                const int row = bm + wr * 64 + m * 16 + lh * 4 + j;
                const float f = acc[m][n][j] + bv;
                if (MODE == 0) {
                    ((float*)Cout)[(size_t)row * GN + col] = f;
                } else {
                    const int b = row >> 10, s = row & 1023;
                    const int h = col >> 6,  d = col & 63;
                    if (MODE == 1) {
                        _Float16 hi, lo;
                        split_f16(f * scale, hi, lo);
                        _Float16* q2 = (_Float16*)Cout +
                            (((size_t)(b * HEADS + h) * SEQL + s) * 128 + d);
                        q2[0]  = hi;
                        q2[64] = lo;
                    } else if (MODE == 2) {
                        ((_Float16*)Cout)[((size_t)(b * HEADS + h) * HDIM + d) * SEQL + s] =
                            (_Float16)f;
                    } else {
                        ((_Float16*)Cout)[((size_t)(b * HEADS + h) * SEQL + s) * HDIM + d] =
                            (_Float16)f;
                    }
                }
            }
        }
    }
}

// ---------------------------------------------------------------------------
// Flash attention v3 (fp16): swapped QK^T (mfma(K,Q)), lane owns one q row's
// scores; softmax in-register (2 shfls); P redistributed to PV A-frags via
// shfl (no P LDS). Scores = Khi*(Qhi+Qlo) 2-term; PV single-fp16 V.
// Q2: [b][h][s][128] hi|lo.  K2: [b][h][s][64] hi.  VT: [b][h][d][1024].
// LDS: K tile 8KB + V tile 8KB, XOR-swizzled via pre-swizzled global source.
// ---------------------------------------------------------------------------
#define KT 64

__global__ __launch_bounds__(256, 6)
void attn_mfma(const _Float16* __restrict__ Q2, const _Float16* __restrict__ K2,
               const _Float16* __restrict__ VT, _Float16* __restrict__ Ab2)
{
    __shared__ __align__(16) char KsB[8192];    // [64 k][64 d' hi] swizzled
    __shared__ __align__(16) char VsB[8192];    // [64 d][64 s]     swizzled

    const int tid  = threadIdx.x;
    const int w    = tid >> 6;
    const int lane = tid & 63;
    const int lr = lane & 15;
    const int lh = lane >> 4;
    const int qt0 = blockIdx.x * 64;
    const int bh  = blockIdx.y;
    const int b   = bh >> 4;

    const _Float16* Qg = Q2 + (size_t)bh * SEQL * 128;
    const _Float16* Kg = K2 + (size_t)bh * SEQL * 64;
    const _Float16* Vg = VT + (size_t)bh * HDIM * SEQL;

    // Q fragments straight from global: row = qt0 + w*16 + lr
    // kk 0..1 = hi d'0-63, kk 2..3 = lo d'0-63
    f16x8 qf[4];
    {
        const _Float16* qrow = Qg + (size_t)(qt0 + w * 16 + lr) * 128 + lh * 8;
        #pragma unroll
        for (int kk = 0; kk < 4; ++kk)
            qf[kk] = *reinterpret_cast<const f16x8*>(qrow + kk * 32);
    }

    f32x4 oacc[4];                       // O[q=4lh+j][d=nd*16+lr]
    #pragma unroll
    for (int nd = 0; nd < 4; ++nd) oacc[nd] = (f32x4){0.f, 0.f, 0.f, 0.f};
    float m_run = -1e30f, l_run = 0.f;   // for q row = lr (this wave)

    const int s0 = lr + 32 * (lh & 1);   // shfl source lanes
    const int s1 = s0 + 16;
    const bool hi_n = (lh >> 1) != 0;

    for (int kt = 0; kt < SEQL / KT; ++kt) {
        // stage K tile [64 k][64 d'] and V tile [64 d][64 s], swizzled source
        #pragma unroll
        for (int i = 0; i < 2; ++i) {
            const int idx = tid + i * 256;                 // 0..511
            const int r   = idx >> 3;                      // 0..63
            const int cb  = ((idx & 7) * 16) ^ ((r & 7) << 4);
            gload_lds16(Kg + (size_t)(kt * KT + r) * 64 + cb / 2,
                        KsB + i * 4096 + w * 1024);
        }
        #pragma unroll
        for (int i = 0; i < 2; ++i) {
            const int idx = tid + i * 256;
            const int r   = idx >> 3;                      // d row
            const int cb  = ((idx & 7) * 16) ^ ((r & 7) << 4);
            gload_lds16(Vg + (size_t)r * SEQL + kt * KT + cb / 2,
                        VsB + i * 4096 + w * 1024);
        }
        __syncthreads();

        // QK^T swapped: sc[n][reg] = S[k = 16n+4lh+reg][q = lr]
        // 2-term: khi*qhi + khi*qlo  (4 MFMA per 16x16 block)
        f32x4 sc[4];
        #pragma unroll
        for (int n = 0; n < 4; ++n) {
            const int row = n * 16 + lr;
            f16x8 kf[2];
            #pragma unroll
            for (int kk = 0; kk < 2; ++kk) {
                const int off = row * 128 + ((kk * 64 + lh * 16) ^ ((row & 7) << 4));
                kf[kk] = *reinterpret_cast<const f16x8*>(KsB + off);
            }
            f32x4 s = (f32x4){0.f, 0.f, 0.f, 0.f};
            s = __builtin_amdgcn_mfma_f32_16x16x32_f16(kf[0], qf[0], s, 0, 0, 0);
            s = __builtin_amdgcn_mfma_f32_16x16x32_f16(kf[1], qf[1], s, 0, 0, 0);
            s = __builtin_amdgcn_mfma_f32_16x16x32_f16(kf[0], qf[2], s, 0, 0, 0);
            s = __builtin_amdgcn_mfma_f32_16x16x32_f16(kf[1], qf[3], s, 0, 0, 0);
            sc[n] = s;
        }

        // online softmax for q = lr (16 values in-lane, combine 4 lh-groups)
        float pm = sc[0][0];
        #pragma unroll
        for (int n = 0; n < 4; ++n)
            #pragma unroll
            for (int j = 0; j < 4; ++j) pm = fmaxf(pm, sc[n][j]);
        pm = fmaxf(pm, __shfl_xor(pm, 16));
        pm = fmaxf(pm, __shfl_xor(pm, 32));
        const float mn    = fmaxf(m_run, pm);
        const float alpha = __expf(m_run - mn);
        m_run = mn;

        float p[4][4], ps = 0.f;
        #pragma unroll
        for (int n = 0; n < 4; ++n)
            #pragma unroll
            for (int j = 0; j < 4; ++j) {
                p[n][j] = __expf(sc[n][j] - mn);
                ps += p[n][j];
            }
        ps += __shfl_xor(ps, 16);
        ps += __shfl_xor(ps, 32);
        l_run = l_run * alpha + ps;

        // pack P to fp16 dwords: pk[n][0]=(reg0,reg1), pk[n][1]=(reg2,reg3)
        unsigned pk[4][2];
        #pragma unroll
        for (int n = 0; n < 4; ++n) {
            pk[n][0] = pack_f16(p[n][0], p[n][1]);
            pk[n][1] = pack_f16(p[n][2], p[n][3]);
        }

        // redistribute into A-frags pa[ks] = P[q=lr][k = 32ks+8lh .. +7]
        unsigned pa[2][4];
        #pragma unroll
        for (int ks = 0; ks < 2; ++ks) {
            const unsigned a0 = __shfl(pk[2 * ks][0],     s0);
            const unsigned b0 = __shfl(pk[2 * ks + 1][0], s0);
            const unsigned a1 = __shfl(pk[2 * ks][1],     s0);
            const unsigned b1 = __shfl(pk[2 * ks + 1][1], s0);
            const unsigned a2 = __shfl(pk[2 * ks][0],     s1);
            const unsigned b2 = __shfl(pk[2 * ks + 1][0], s1);
            const unsigned a3 = __shfl(pk[2 * ks][1],     s1);
            const unsigned b3 = __shfl(pk[2 * ks + 1][1], s1);
            pa[ks][0] = hi_n ? b0 : a0;
            pa[ks][1] = hi_n ? b1 : a1;
            pa[ks][2] = hi_n ? b2 : a2;
            pa[ks][3] = hi_n ? b3 : a3;
        }

        // rescale oacc rows (q = 4lh+j) by that row's alpha
        float av[4];
        #pragma unroll
        for (int j = 0; j < 4; ++j)
            av[j] = __shfl(alpha, (lane & 48) | ((4 * lh + j) & 15));
        #pragma unroll
        for (int nd = 0; nd < 4; ++nd)
            #pragma unroll
            for (int j = 0; j < 4; ++j) oacc[nd][j] *= av[j];

        // PV: O += P * V   (single-fp16 V)
        #pragma unroll
        for (int ks = 0; ks < 2; ++ks) {
            const f16x8 pf = *reinterpret_cast<const f16x8*>(&pa[ks][0]);
            #pragma unroll
            for (int nd = 0; nd < 4; ++nd) {
                const int row = nd * 16 + lr;
                const int off = row * 128 +
                    ((ks * 64 + lh * 16) ^ ((row & 7) << 4));
                const f16x8 vf = *reinterpret_cast<const f16x8*>(VsB + off);
                oacc[nd] = __builtin_amdgcn_mfma_f32_16x16x32_f16(
                    pf, vf, oacc[nd], 0, 0, 0);
            }
        }
        __syncthreads();   // all waves done with Ks/Vs before next stage
    }

    // epilogue: O = acc/l, write hi|lo fp16 into Ab2 [8192][2048]
    const int h = bh & (HEADS - 1);
    #pragma unroll
    for (int j = 0; j < 4; ++j) {
        const float lv = __shfl(l_run, (lane & 48) | ((4 * lh + j) & 15));
        const float rl = 1.f / lv;
        const size_t gm = (size_t)b * SEQL + qt0 + w * 16 + 4 * lh + j;
        #pragma unroll
        for (int nd = 0; nd < 4; ++nd) {
            const int e = h * 64 + nd * 16 + lr;
            _Float16 hi, lo;
            split_f16(oacc[nd][j] * rl, hi, lo);
            Ab2[gm * KK2 + e]         = hi;
            Ab2[gm * KK2 + EMBED + e] = lo;
        }
    }
}

// ---------------------------------------------------------------------------
extern "C" void kernel_launch(void* const* d_in, const int* in_sizes, int n_in,
                              void* d_out, int out_size, void* d_ws, size_t ws_size,
                              hipStream_t stream)
{
    const float* x  = (const float*)d_in[0];
    const float* wq = (const float*)d_in[1];
    const float* bq = (const float*)d_in[2];
    const float* wk = (const float*)d_in[3];
    const float* bk = (const float*)d_in[4];
    const float* wv = (const float*)d_in[5];
    const float* bv = (const float*)d_in[6];
    const float* wo = (const float*)d_in[7];
    const float* bo = (const float*)d_in[8];
    float* out = (float*)d_out;

    // workspace layout (Ab2 aliases x2: x2 dead after the V GEMM)
    char* p = (char*)d_ws;
    _Float16* x2  = (_Float16*)p;  p += (size_t)MROWS * KK2 * 2;                // 33.5 MB
    _Float16* wq2 = (_Float16*)p;  p += (size_t)EMBED * KK2 * 2;                //  4.2 MB
    _Float16* wk2 = (_Float16*)p;  p += (size_t)EMBED * KK2 * 2;
    _Float16* wv2 = (_Float16*)p;  p += (size_t)EMBED * KK2 * 2;
    _Float16* wo2 = (_Float16*)p;  p += (size_t)EMBED * KK2 * 2;
    _Float16* Q2  = (_Float16*)p;  p += (size_t)BATCH * HEADS * SEQL * 128 * 2;   // 33.5 MB
    _Float16* K2  = (_Float16*)p;  p += (size_t)BATCH * HEADS * SEQL * 64 * 2;    // 16.8 MB
    _Float16* VT  = (_Float16*)p;  p += (size_t)BATCH * HEADS * HDIM * SEQL * 2;  // 16.8 MB
    _Float16* Ab2 = x2;

    const dim3 blk(256);
    cvt_split<<<dim3(MROWS), blk, 0, stream>>>(x,  x2);
    cvt_split<<<dim3(EMBED), blk, 0, stream>>>(wq, wq2);
    cvt_split<<<dim3(EMBED), blk, 0, stream>>>(wk, wk2);
    cvt_split<<<dim3(EMBED), blk, 0, stream>>>(wv, wv2);
    cvt_split<<<dim3(EMBED), blk, 0, stream>>>(wo, wo2);

    const dim3 gg(MROWS / 128, EMBED / 128);   // 64 x 8
    const float scale = 0.125f;                // 1/sqrt(HDIM), folded into Q
    gemm_mfma<1><<<gg, blk, 0, stream>>>(x2, wq2, bq, Q2, scale);
    gemm_mfma<3><<<gg, blk, 0, stream>>>(x2, wk2, bk, K2, 1.0f);
    gemm_mfma<2><<<gg, blk, 0, stream>>>(x2, wv2, bv, VT, 1.0f);

    attn_mfma<<<dim3(SEQL / 64, BATCH * HEADS), blk, 0, stream>>>(Q2, K2, VT, Ab2);

    gemm_mfma<0><<<gg, blk, 0, stream>>>(Ab2, wo2, bo, out, 1.0f);
}